// Round 8
// baseline (21302.344 us; speedup 1.0000x reference)
//
#include <hip/hip_runtime.h>
#include <hip/hip_bf16.h>

// Persistent-kernel seq2seq (enc LSTM -> attn decoder -> CE loss) for MI355X.
// R8: (1) parallel-flag barriers (store+coalesced poll, no RMW chain);
// (2) q-phase eliminated via P = enc_hs @ attW precomputed into LDS
//     (scores = P . h_new), decoder = 2 phases/step; acc pass streams enc
//     from MALL with 4-deep ILP; (3) cross-barrier prefetch of h-fragments.

#define NWG 256
#define NT  256

typedef unsigned short u16;
typedef unsigned int   u32;
typedef unsigned long long u64;
typedef __attribute__((ext_vector_type(4))) float f4;
typedef __attribute__((ext_vector_type(8))) short s8;

constexpr int Bv=128, Lc=512, Le=512, Hd=512, Vc=128;
constexpr int KE=640, KD=1152;
constexpr int CAP = 144;     // LDS-resident P positions per WG
constexpr int SPN = 24;      // global spill positions per WG (covers cn<=336)

// ---- workspace layout (bytes) ----
constexpr size_t O_WENC = 4096;                                // bf16 [2048][640]
constexpr size_t O_WDEC = O_WENC + (size_t)2048*KE*2;          // bf16 [2048][1152] orig (t=0)
constexpr size_t O_WDF  = O_WDEC + (size_t)2048*KD*2;          // bf16 [2048][1152] folded
constexpr size_t O_ATWT = O_WDF  + (size_t)2048*KD*2;          // bf16 [512][512] attW^T (kout-major)
constexpr size_t O_OUTW = O_ATWT + (size_t)512*512*2;          // bf16 [512][1024]
constexpr size_t O_VOCW = O_OUTW + (size_t)512*1024*2;         // bf16 [128][512]
constexpr size_t O_BE   = O_VOCW + (size_t)128*512*2;          // f32[2048]
constexpr size_t O_BD   = O_BE + 8192;                         // f32[2048] orig
constexpr size_t O_BDF  = O_BD + 8192;                         // f32[2048] folded
constexpr size_t O_H    = O_BDF + 8192;                        // bf16 [2][128][512]
constexpr size_t O_TNH  = O_H + (size_t)2*128*512*2;           // bf16 [2][128][512]
constexpr size_t O_PFX  = O_TNH + (size_t)2*128*512*2;         // u32 [128][512]
constexpr size_t O_CNT  = O_PFX + (size_t)128*512*4;           // u32[128]
constexpr size_t O_PMS  = O_CNT + 512;                         // u64 [128][2]
constexpr size_t O_PACC = O_PMS + 2048;                        // bf16 [128][2][512]
constexpr size_t O_REC  = O_PACC + (size_t)256*512*2;          // f32 [2][128][2][4]
constexpr size_t O_LOSS = O_REC + (size_t)2*128*2*4*4;         // f32[2]
constexpr size_t O_ENC  = O_LOSS + 256;                        // bf16 [128][512][512]
constexpr size_t O_PSP  = O_ENC + (size_t)128*512*512*2;       // bf16 [256][SPN][512] P spill

// ---- LDS: [0, CAP KB) = P slice; [SC, SC+16K) = phase scratch ----
constexpr int SC       = CAP*1024;             // 147456
constexpr int SM_BYTES = SC + 16384;           // 163840 (160 KB)

struct P {
  const float *C; const int *Cpad; const int *E; const float *Eemb;
  const float *eWih,*eWhh,*ebih,*ebhh;
  const float *dWih,*dWhh,*dbih,*dbhh;
  const float *attW,*outW,*outb,*vocW,*vocb;
  char* ws; float* out;
};

__device__ inline u16 f2bf(float x){
  u32 u = __float_as_uint(x);
  return (u16)((u + 0x7fffu + ((u>>16)&1u)) >> 16);
}
__device__ inline float bf2f(u16 b){ return __uint_as_float(((u32)b)<<16); }
__device__ inline float sigm(float x){ return 1.f/(1.f+expf(-x)); }
__device__ inline f4 MM(s8 a, s8 b, f4 c){
  return __builtin_amdgcn_mfma_f32_16x16x32_bf16(a, b, c, 0, 0, 0);
}
// device-scope relaxed (cache-bypass) helpers
__device__ inline u64 ld64a(const void* p){
  return __hip_atomic_load((const u64*)p, __ATOMIC_RELAXED, __HIP_MEMORY_SCOPE_AGENT);
}
__device__ inline u32 ld32u(const void* p){
  return __hip_atomic_load((const u32*)p, __ATOMIC_RELAXED, __HIP_MEMORY_SCOPE_AGENT);
}
__device__ inline void st64a(void* p, u64 v){
  __hip_atomic_store((u64*)p, v, __ATOMIC_RELAXED, __HIP_MEMORY_SCOPE_AGENT);
}
__device__ inline void st32a(void* p, u32 v){
  __hip_atomic_store((u32*)p, v, __ATOMIC_RELAXED, __HIP_MEMORY_SCOPE_AGENT);
}
__device__ inline s8 ld16a(const void* p){
  union { u64 q[2]; s8 v; } u;
  u.q[0] = ld64a(p); u.q[1] = ld64a((const char*)p + 8);
  return u.v;
}
__device__ inline s8 cvt8(const float* p){
  f4 u = *(const f4*)p, v = *(const f4*)(p+4);
  s8 r;
  r[0]=(short)f2bf(u[0]); r[1]=(short)f2bf(u[1]); r[2]=(short)f2bf(u[2]); r[3]=(short)f2bf(u[3]);
  r[4]=(short)f2bf(v[0]); r[5]=(short)f2bf(v[1]); r[6]=(short)f2bf(v[2]); r[7]=(short)f2bf(v[3]);
  return r;
}
__device__ inline float wredmax(float v){
  #pragma unroll
  for (int m=32;m;m>>=1) v = fmaxf(v, __shfl_xor(v,m,64));
  return v;
}
__device__ inline float wredsum(float v){
  #pragma unroll
  for (int m=32;m;m>>=1) v += __shfl_xor(v,m,64);
  return v;
}

extern "C" __global__ void __launch_bounds__(NT,1) k_main(P p)
{
  extern __shared__ char sm[];
  const int wg = blockIdx.x, tid = threadIdx.x;
  const int gt = wg*NT + tid;
  // weight-sharing set (same cg) co-resident on one XCD (wg mod 8 = cg mod 8)
  const int rg = wg >> 5, cg = wg & 31;

  char* ws = p.ws;
  u32*  slotA = (u32*)ws;                       // [256] grid barrier slots
  u32*  slotR = (u32*)(ws + 1024 + rg*128);     // [32] rowgroup slots
  u16*  wenc = (u16*)(ws + O_WENC);
  u16*  wdec = (u16*)(ws + O_WDEC);
  u16*  wdf  = (u16*)(ws + O_WDF);
  u16*  atwt = (u16*)(ws + O_ATWT);
  u16*  outw = (u16*)(ws + O_OUTW);
  u16*  vocw = (u16*)(ws + O_VOCW);
  float* be  = (float*)(ws + O_BE);
  float* bd  = (float*)(ws + O_BD);
  float* bdf = (float*)(ws + O_BDF);
  u16*  hbf  = (u16*)(ws + O_H);
  u16*  tnhb = (u16*)(ws + O_TNH);
  u32*  pfx  = (u32*)(ws + O_PFX);
  u32*  cntp = (u32*)(ws + O_CNT);
  u64*  pms  = (u64*)(ws + O_PMS);
  u16*  pacc16 = (u16*)(ws + O_PACC);
  float* rec = (float*)(ws + O_REC);
  float* losp= (float*)(ws + O_LOSS);
  u16*  encc = (u16*)(ws + O_ENC);
  u16*  spl  = (u16*)(ws + O_PSP) + (size_t)wg*SPN*Hd;

  u32 genA = 0, genG = 0;
  // grid barrier: release-flush, per-WG slot store, parallel poll, acquire-inv
  auto GBall = [&](){
    genA++;
    __syncthreads();                      // drains all stores to L2
    if (tid == 0){
      __builtin_amdgcn_fence(__ATOMIC_RELEASE, "agent");   // wbl2
      st32a(slotA + wg, genA);
    }
    if (tid < 64){
      bool done = false;
      while (!done){
        u32 v0 = ld32u(slotA + tid);
        u32 v1 = ld32u(slotA + 64 + tid);
        u32 v2 = ld32u(slotA + 128 + tid);
        u32 v3 = ld32u(slotA + 192 + tid);
        done = __all((v0>=genA)&&(v1>=genA)&&(v2>=genA)&&(v3>=genA));
        if (!done) __builtin_amdgcn_s_sleep(4);
      }
      __builtin_amdgcn_fence(__ATOMIC_ACQUIRE, "agent");   // inv L1/L2
    }
    __syncthreads();
  };
  // rowgroup barrier: fence-free (all cross-WG data moves via bypass atomics).
  // arrival = plain slot store (syncthreads already drained bypass stores);
  // poll = one coalesced 128B MALL read per iteration.
  auto RGB = [&](){
    genG++;
    __syncthreads();
    if (tid == 0) st32a(slotR + cg, genG);
    if (tid < 64){
      bool done = false;
      while (!done){
        u32 v = ld32u(slotR + (tid & 31));
        done = __all(v >= genG);
        if (!done) __builtin_amdgcn_s_sleep(2);
      }
      __builtin_amdgcn_fence(__ATOMIC_ACQUIRE, "workgroup");  // compiler order
    }
    __syncthreads();
  };

  // ================= phase 0: convert, fold, init =================
  for (int i = gt; i < 2048*KE; i += NWG*NT){
    int row = i / KE, k = i - row*KE;
    float v = (k < 128) ? p.eWih[row*128 + k] : p.eWhh[row*512 + (k-128)];
    wenc[i] = f2bf(v);
  }
  for (int i = gt; i < 2048*KD; i += NWG*NT){
    int row = i / KD, k = i - row*KD;
    float v = (k < 640) ? p.dWih[row*640 + k] : p.dWhh[row*512 + (k-640)];
    wdec[i] = f2bf(v);
  }
  for (int i = gt; i < 512*512;  i += NWG*NT){
    int kk = i >> 9, j = i & 511;
    atwt[i] = f2bf(p.attW[(size_t)j*512 + kk]);   // atwt[k][j] = attW[j][k]
  }
  for (int i = gt; i < 512*1024; i += NWG*NT) outw[i] = f2bf(p.outW[i]);
  for (int i = gt; i < 128*512;  i += NWG*NT) vocw[i] = f2bf(p.vocW[i]);
  for (int i = gt; i < 2048;     i += NWG*NT){ be[i] = p.ebih[i]+p.ebhh[i]; bd[i] = p.dbih[i]+p.dbhh[i]; }
  { u32* hz = (u32*)hbf; for (int i = gt; i < 65536; i += NWG*NT) hz[i] = 0; }
  if (gt == 0){ losp[0] = 0.f; losp[1] = 0.f; }

  // --- W2 = dWv @ outW fold; wdf/bdf build. WG owns 8 gate-rows. ---
  {
    const int g0 = wg*8;
    float* dv = (float*)sm;                      // [8][512] f32 (P region, pre-decoder)
    for (int i = tid; i < 8*512; i += NT)
      dv[i] = p.dWih[(size_t)(g0 + (i>>9))*640 + 128 + (i&511)];
    __syncthreads();
    float wa[8][4];
    #pragma unroll
    for (int r=0;r<8;r++){ wa[r][0]=0;wa[r][1]=0;wa[r][2]=0;wa[r][3]=0; }
    for (int o = 0; o < 512; o++){
      float b0 = p.outW[(size_t)o*1024 + tid];
      float b1 = p.outW[(size_t)o*1024 + 256 + tid];
      float b2 = p.outW[(size_t)o*1024 + 512 + tid];
      float b3 = p.outW[(size_t)o*1024 + 768 + tid];
      #pragma unroll
      for (int r=0;r<8;r++){
        float d = dv[r*512+o];
        wa[r][0] += d*b0; wa[r][1] += d*b1; wa[r][2] += d*b2; wa[r][3] += d*b3;
      }
    }
    #pragma unroll
    for (int r=0;r<8;r++){
      int g = g0 + r;
      #pragma unroll
      for (int j=0;j<4;j++){
        int c = tid + 256*j;
        if (c < 512) wdf[(size_t)g*KD + 128 + c] = f2bf(p.dWhh[(size_t)g*512 + c] + wa[r][j]);
        else         wdf[(size_t)g*KD + 640 + (c-512)] = f2bf(wa[r][j]);
      }
    }
    for (int i = tid; i < 8*128; i += NT){
      int r = i >> 7, k = i & 127;
      wdf[(size_t)(g0+r)*KD + k] = f2bf(p.dWih[(size_t)(g0+r)*640 + k]);
    }
    if (tid < 8){
      int g = g0 + tid;
      float s = p.dbih[g] + p.dbhh[g];
      for (int o = 0; o < 512; o++) s += dv[tid*512+o]*p.outb[o];
      bdf[g] = s;
    }
    __syncthreads();
  }

  if (wg < 128){
    int* padl = (int*)(sm + SC);
    for (int i = tid; i < 512; i += NT) padl[i] = p.Cpad[wg*512 + i];
    __syncthreads();
    if (tid == 0){
      u32 run = 0;
      for (int tt = 0; tt < 512; tt++){ pfx[wg*512+tt] = run; if (padl[tt] == 0) run++; }
      cntp[wg] = run;
    }
    __syncthreads();
  }
  GBall();

  const int l  = tid & 63, wv = tid >> 6;
  const int n2 = wv >> 1, k2 = wv & 1;
  const int kl = (l>>4) << 3;
  const int ar = rg*16 + (l&15);
  float cst = 0.f;
  float accN = 0.f, accC = 0.f;

  // attention ownership: 2 WGs per batch row
  const int rowA = rg*16 + (cg >> 1), halfA = cg & 1;
  const int cnA = (int)cntp[rowA], c2A = cnA >> 1;
  const int loA = halfA ? c2A : 0;
  const int mynA = (halfA ? cnA : c2A) - loA;
  const int ncapA = mynA < CAP ? mynA : CAP;
  const int limA  = mynA < CAP+SPN ? mynA : CAP+SPN;
  u16* eP = (u16*)sm;   // LDS P slice [CAP][512] bf16 (projected enc)

  // CE record for step tl (this WG's vocab half of its row)
  auto CEREC = [&](int tl){
    u32* th16 = (u32*)(sm + SC + 11776);      // raw bf16x2 [256]
    float* lgp = (float*)(sm + SC + 12800);   // [4][64]
    float* lgh = (float*)(sm + SC + 13824);   // [64]
    const u16* tb = tnhb + (size_t)(tl&1)*Bv*Hd + (size_t)rowA*Hd;
    th16[tid] = ld32u(tb + 2*tid);
    __syncthreads();
    {
      int v = tid & 63, ksl = tid >> 6;
      int gv = halfA*64 + v;
      const u16* wp = vocw + (size_t)gv*Hd + ksl*128;
      const u16* hp = (const u16*)th16 + ksl*128;
      float acc = 0.f;
      #pragma unroll 4
      for (int j = 0; j < 16; j++){
        s8 wv8 = *(const s8*)(wp + j*8);
        #pragma unroll
        for (int q = 0; q < 8; q++) acc += bf2f((u16)wv8[q]) * bf2f(hp[j*8+q]);
      }
      lgp[ksl*64 + v] = acc;
    }
    __syncthreads();
    if (tid < 64){
      int gv = halfA*64 + tid;
      float lv = lgp[tid] + lgp[64+tid] + lgp[128+tid] + lgp[192+tid] + p.vocb[gv];
      lgh[tid] = lv;
      float m = wredmax(lv);
      float s = wredsum(expf(lv - m));
      if (tid == 0){
        int tgt = p.E[rowA*Le + tl + 1];
        float tlg = (tgt >= halfA*64 && tgt < halfA*64+64) ? lgh[tgt - halfA*64] : 0.f;
        float* rp = rec + ((size_t)(tl&1)*256 + rowA*2 + halfA)*4;
        union { u64 q; float f[2]; } pk; pk.f[0]=m; pk.f[1]=s;
        st64a(rp, pk.q);
        st32a(rp+2, __float_as_uint(tlg));
      }
    }
    __syncthreads();
  };
  auto COMB = [&](int tl){
    int tgt = p.E[rowA*Le + tl + 1];
    if (tgt != 0){
      const float* rp = rec + ((size_t)(tl&1)*256 + rowA*2)*4;
      union { u64 q; float f[2]; } a, b;
      a.q = ld64a(rp); b.q = ld64a(rp+4);
      float tA = __uint_as_float(ld32u(rp+2)), tB = __uint_as_float(ld32u(rp+6));
      float M = fmaxf(a.f[0], b.f[0]);
      float S = a.f[1]*expf(a.f[0]-M) + b.f[1]*expf(b.f[0]-M);
      accN += logf(S) + M - (tA + tB);
      accC += 1.f;
    }
  };

  // ================= encoder (B-fragments from global wenc) =================
  const int gR0 = (n2*2+0)*512 + cg*16 + (l&15);
  const int gR1 = (n2*2+1)*512 + cg*16 + (l&15);

  for (int t = 0; t < Lc; t++){
    const u16* hold = hbf + (t&1)*Bv*Hd;
    u16* hnew       = hbf + ((t+1)&1)*Bv*Hd;
    s8 a[10];
    #pragma unroll
    for (int ks = 0; ks < 10; ks++){
      int k = k2*320 + ks*32 + kl;
      if (k < 128) a[ks] = cvt8(p.C + ((size_t)ar*Lc + t)*Vc + k);
      else         a[ks] = ld16a(hold + (size_t)ar*Hd + (k-128));
    }
    f4 acc0 = {0,0,0,0}, acc1 = {0,0,0,0};
    #pragma unroll
    for (int ks = 0; ks < 10; ks++){
      int k = k2*320 + ks*32 + kl;
      acc0 = MM(a[ks], *(const s8*)(wenc + (size_t)gR0*KE + k), acc0);
      acc1 = MM(a[ks], *(const s8*)(wenc + (size_t)gR1*KE + k), acc1);
    }
    float* exch = (float*)(sm + SC);
    #pragma unroll
    for (int r = 0; r < 4; r++){
      int row = ((l>>4)<<2) + r;
      exch[((k2*4 + n2*2+0)*16 + row)*16 + (l&15)] = acc0[r];
      exch[((k2*4 + n2*2+1)*16 + row)*16 + (l&15)] = acc1[r];
    }
    __syncthreads();
    {
      int row = tid >> 4, u = tid & 15;
      int gb = cg*16 + u;
      float gi = exch[((0)*16+row)*16+u] + exch[((4)*16+row)*16+u] + be[0*512+gb];
      float gf = exch[((1)*16+row)*16+u] + exch[((5)*16+row)*16+u] + be[1*512+gb];
      float gg = exch[((2)*16+row)*16+u] + exch[((6)*16+row)*16+u] + be[2*512+gb];
      float go = exch[((3)*16+row)*16+u] + exch[((7)*16+row)*16+u] + be[3*512+gb];
      float fi = sigm(gi), ff = sigm(gf), fg = tanhf(gg), fo = sigm(go);
      cst = ff*cst + fi*fg;
      float hn = fo * tanhf(cst);
      int b = rg*16 + row;
      u32 hb = f2bf(hn);
      u32 nb = __shfl_xor((int)hb, 1, 64);
      if ((tid & 1) == 0){
        u32 pk = hb | (nb << 16);
        st32a(hnew + (size_t)b*Hd + gb, pk);
        if (p.Cpad[b*Lc + t] == 0){
          u32 pos = pfx[b*Lc + t];
          st32a(encc + ((size_t)b*Lc + pos)*Hd + gb, pk);
        }
      }
    }
    RGB();
  }

  GBall();   // flush+inv once: encc/wdf/etc readable CACHED hereafter

  // ======== projection: P[i][k] = sum_j enc[i][j] * attW[j][k] ========
  {
    const u16* erow = encc + ((size_t)rowA*Lc + loA)*Hd;
    for (int it = 0; it*16 < limA; it++){
      s8 afr[16];
      const u16* ap = erow + (size_t)(it*16 + (l&15))*Hd;
      #pragma unroll
      for (int ks = 0; ks < 16; ks++) afr[ks] = *(const s8*)(ap + ks*32 + kl);
      for (int ot = 0; ot < 8; ot++){
        int kout0 = wv*128 + ot*16;
        f4 acc = {0,0,0,0};
        #pragma unroll
        for (int ks = 0; ks < 16; ks++)
          acc = MM(afr[ks], *(const s8*)(atwt + (size_t)(kout0 + (l&15))*Hd + ks*32 + kl), acc);
        #pragma unroll
        for (int r = 0; r < 4; r++){
          int prow = it*16 + ((l>>4)<<2) + r;
          int pcol = kout0 + (l&15);
          if (prow < limA){
            u16 pv = f2bf(acc[r]);
            if (prow < CAP) eP[(size_t)prow*Hd + pcol] = pv;
            else            spl[(size_t)(prow-CAP)*Hd + pcol] = pv;
          }
        }
      }
    }
    __syncthreads();
  }

  // ================= decoder: 2 phases/step =================
  float* exch = (float*)(sm + SC);            // [8][16][16] f32 (8 KB)
  float* vex  = (float*)(sm + SC + 8192);     // [4][16][16] f32 (4 KB)
  float* sc2  = (float*)(sm + SC + 12288);    // [16][2] f32
  s8 aH[14];                                  // cross-barrier h prefetch

  for (int t = 0; t < Le-1; t++){
    const u16* hold = hbf + (t&1)*Bv*Hd;
    u16* hnew       = hbf + ((t+1)&1)*Bv*Hd;

    // ======== P1: gates (+ lagged Vnew_{t-1}); B from global ========
    if (t == 0){
      s8 a[10];
      #pragma unroll
      for (int ks = 0; ks < 10; ks++){
        int ke = (k2==0) ? ((ks<4) ? ks*32+kl : 640 + (ks-4)*32 + kl)
                         : (832 + ks*32 + kl);
        if (ke < 128) a[ks] = cvt8(p.Eemb + ((size_t)ar*Le + 0)*Vc + ke);
        else          a[ks] = ld16a(hold + (size_t)ar*Hd + (ke-640));
      }
      f4 acc0 = {0,0,0,0}, acc1 = {0,0,0,0};
      #pragma unroll
      for (int ks = 0; ks < 10; ks++){
        int ke = (k2==0) ? ((ks<4) ? ks*32+kl : 640 + (ks-4)*32 + kl)
                         : (832 + ks*32 + kl);
        acc0 = MM(a[ks], *(const s8*)(wdec + (size_t)gR0*KD + ke), acc0);
        acc1 = MM(a[ks], *(const s8*)(wdec + (size_t)gR1*KD + ke), acc1);
      }
      #pragma unroll
      for (int r = 0; r < 4; r++){
        int row = ((l>>4)<<2) + r;
        exch[((k2*4 + n2*2+0)*16 + row)*16 + (l&15)] = acc0[r];
        exch[((k2*4 + n2*2+1)*16 + row)*16 + (l&15)] = acc1[r];
      }
      __syncthreads();
      {
        int row = tid >> 4, u = tid & 15;
        int gb = cg*16 + u;
        float gi = exch[((0)*16+row)*16+u] + exch[((4)*16+row)*16+u] + bd[0*512+gb];
        float gf = exch[((1)*16+row)*16+u] + exch[((5)*16+row)*16+u] + bd[1*512+gb];
        float gg = exch[((2)*16+row)*16+u] + exch[((6)*16+row)*16+u] + bd[2*512+gb];
        float go = exch[((3)*16+row)*16+u] + exch[((7)*16+row)*16+u] + bd[3*512+gb];
        float fi = sigm(gi), ff = sigm(gf), fg = tanhf(gg), fo = sigm(go);
        cst = ff*cst + fi*fg;
        float hn = fo * tanhf(cst);
        u32 hb = f2bf(hn);
        u32 nb = __shfl_xor((int)hb, 1, 64);
        if ((tid & 1) == 0)
          st32a(hnew + (size_t)(rg*16+row)*Hd + gb, hb | (nb << 16));
      }
    } else {
      if (tid < 16){
        union { u64 q; float f[2]; } uA, uB;
        uA.q = ld64a(pms + (rg*16+tid)*2 + 0);
        uB.q = ld64a(pms + (rg*16+tid)*2 + 1);
        float M = fmaxf(uA.f[0], uB.f[0]);
        float eA = (uA.f[0] > -1e29f) ? expf(uA.f[0]-M) : 0.f;
        float eB = (uB.f[0] > -1e29f) ? expf(uB.f[0]-M) : 0.f;
        float den = uA.f[1]*eA + uB.f[1]*eB;
        sc2[tid*2]   = eA/den;
        sc2[tid*2+1] = eB/den;
      }
      __syncthreads();
      const float scA = sc2[(l&15)*2], scB = sc2[(l&15)*2+1];
      const u16* pA = pacc16 + (size_t)(ar*2+0)*Hd;
      const u16* pB = pacc16 + (size_t)(ar*2+1)*Hd;
      s8 a[18];
      if (k2 == 0){
        #pragma unroll
        for (int ks = 0; ks < 4; ks++)
          a[ks] = cvt8(p.Eemb + ((size_t)ar*Le + t)*Vc + ks*32 + kl);
        #pragma unroll
        for (int ks = 4; ks < 18; ks++) a[ks] = aH[ks-4];   // prefetched
      } else {
        a[0] = aH[0]; a[1] = aH[1];                          // prefetched
        #pragma unroll
        for (int ks = 2; ks < 18; ks++){
          int k = 576 + ks*32 + kl;                          // [640,1152)
          s8 va = ld16a(pA + (k-640));
          s8 vb = ld16a(pB + (k-640));
          s8 r;
          #pragma unroll
          for (int j = 0; j < 8; j++)
            r[j] = (short)f2bf(scA*bf2f((u16)va[j]) + scB*bf2f((u16)vb[j]));
          a[ks] = r;
        }
      }
      f4 acc0 = {0,0,0,0}, acc1 = {0,0,0,0};
      #pragma unroll
      for (int ks = 0; ks < 18; ks++){
        int k = k2*576 + ks*32 + kl;
        acc0 = MM(a[ks], *(const s8*)(wdf + (size_t)gR0*KD + k), acc0);
        acc1 = MM(a[ks], *(const s8*)(wdf + (size_t)gR1*KD + k), acc1);
      }
      // lagged Vnew_{t-1}: A-fragments (k>=128) are exactly U_{t-1}=[h,attn]
      f4 vac = {0,0,0,0};
      const int colc = cg*16 + (l&15);
      #pragma unroll
      for (int ks = 0; ks < 18; ks++){
        int ck = k2*18 + ks - 4;
        if (ck >= 0 && ((ck & 1) == n2))
          vac = MM(a[ks], *(const s8*)(outw + (size_t)colc*1024 + ck*32 + kl), vac);
      }
      #pragma unroll
      for (int r = 0; r < 4; r++){
        int row = ((l>>4)<<2) + r;
        exch[((k2*4 + n2*2+0)*16 + row)*16 + (l&15)] = acc0[r];
        exch[((k2*4 + n2*2+1)*16 + row)*16 + (l&15)] = acc1[r];
        vex[wv*256 + row*16 + (l&15)] = vac[r];
      }
      __syncthreads();
      {
        int row = tid >> 4, u = tid & 15;
        int gb = cg*16 + u;
        float gi = exch[((0)*16+row)*16+u] + exch[((4)*16+row)*16+u] + bdf[0*512+gb];
        float gf = exch[((1)*16+row)*16+u] + exch[((5)*16+row)*16+u] + bdf[1*512+gb];
        float gg = exch[((2)*16+row)*16+u] + exch[((6)*16+row)*16+u] + bdf[2*512+gb];
        float go = exch[((3)*16+row)*16+u] + exch[((7)*16+row)*16+u] + bdf[3*512+gb];
        float fi = sigm(gi), ff = sigm(gf), fg = tanhf(gg), fo = sigm(go);
        cst = ff*cst + fi*fg;
        float hn = fo * tanhf(cst);
        u32 hb = f2bf(hn);
        u32 nb = __shfl_xor((int)hb, 1, 64);
        if ((tid & 1) == 0)
          st32a(hnew + (size_t)(rg*16+row)*Hd + gb, hb | (nb << 16));
        float v = vex[row*16+u] + vex[256+row*16+u] + vex[512+row*16+u]
                + vex[768+row*16+u] + p.outb[gb];
        u32 tb2 = f2bf(tanhf(v));
        u32 tn2 = __shfl_xor((int)tb2, 1, 64);
        if ((tid & 1) == 0){
          u16* tnw = tnhb + (size_t)((t-1)&1)*Bv*Hd;
          st32a(tnw + (size_t)(rg*16+row)*Hd + gb, tb2 | (tn2 << 16));
        }
      }
    }
    RGB();

    // ======== P2': scores(P.h) + softmax + acc(global enc) + lagged CE ========
    {
      const int ne = limA, ncap = ncapA;
      float* hld = (float*)(sm + SC);             // 2 KB permuted h
      float* scl = (float*)(sm + SC + 2048);      // up to 192 f32
      float* red = (float*)(sm + SC + 2816);      // 4 f32
      float* part= (float*)(sm + SC + 3584);      // [4][512] f32, 8 KB
      {
        u32 hw = ld32u(hnew + (size_t)rowA*Hd + 2*tid);
        int c0 = 2*tid, c1 = c0+1;
        hld[(c0&15)*32 + (c0>>4)] = bf2f((u16)(hw & 0xffffu));
        hld[(c1&15)*32 + (c1>>4)] = bf2f((u16)(hw >> 16));
      }
      __syncthreads();
      const int pg8 = tid >> 5, ln = tid & 31;
      int i = pg8;
      for (; i < ncap; i += 8){
        const u16* e = eP + (size_t)i*Hd + ln*16;
        s8 ev0 = *(const s8*)(e);
        s8 ev1 = *(const s8*)(e+8);
        float s = 0.f;
        #pragma unroll
        for (int j=0;j<8;j++) s += bf2f((u16)ev0[j]) * hld[j*32+ln];
        #pragma unroll
        for (int j=0;j<8;j++) s += bf2f((u16)ev1[j]) * hld[(j+8)*32+ln];
        #pragma unroll
        for (int m=1;m<32;m<<=1) s += __shfl_xor(s, m, 64);
        if (ln == 0) scl[i] = s;
      }
      for (; i < ne; i += 8){
        const u16* e = spl + (size_t)(i-CAP)*Hd + ln*16;
        s8 ev0 = *(const s8*)(e);
        s8 ev1 = *(const s8*)(e+8);
        float s = 0.f;
        #pragma unroll
        for (int j=0;j<8;j++) s += bf2f((u16)ev0[j]) * hld[j*32+ln];
        #pragma unroll
        for (int j=0;j<8;j++) s += bf2f((u16)ev1[j]) * hld[(j+8)*32+ln];
        #pragma unroll
        for (int m=1;m<32;m<<=1) s += __shfl_xor(s, m, 64);
        if (ln == 0) scl[i] = s;
      }
      __syncthreads();
      float mloc = -1e30f;
      for (int i2 = tid; i2 < ne; i2 += NT) mloc = fmaxf(mloc, scl[i2]);
      mloc = wredmax(mloc);
      if ((tid&63)==0) red[tid>>6] = mloc;
      __syncthreads();
      float M = fmaxf(fmaxf(red[0],red[1]), fmaxf(red[2],red[3]));
      __syncthreads();
      float sloc = 0.f;
      for (int i2 = tid; i2 < ne; i2 += NT){ float w = expf(scl[i2]-M); scl[i2]=w; sloc += w; }
      sloc = wredsum(sloc);
      if ((tid&63)==0) red[tid>>6] = sloc;
      __syncthreads();
      float S = red[0]+red[1]+red[2]+red[3];
      // weighted acc over enc (global, MALL-resident), 4-deep ILP
      float a8[8] = {0,0,0,0,0,0,0,0};
      const u16* eb2 = encc + ((size_t)rowA*Lc + loA)*Hd + l*8;
      int ii = wv;
      for (; ii + 12 < ne; ii += 16){
        s8 e0 = *(const s8*)(eb2 + (size_t)(ii   )*Hd);
        s8 e1 = *(const s8*)(eb2 + (size_t)(ii+ 4)*Hd);
        s8 e2 = *(const s8*)(eb2 + (size_t)(ii+ 8)*Hd);
        s8 e3 = *(const s8*)(eb2 + (size_t)(ii+12)*Hd);
        float w0=scl[ii], w1=scl[ii+4], w2=scl[ii+8], w3=scl[ii+12];
        #pragma unroll
        for (int j=0;j<8;j++) a8[j] += w0*bf2f((u16)e0[j]);
        #pragma unroll
        for (int j=0;j<8;j++) a8[j] += w1*bf2f((u16)e1[j]);
        #pragma unroll
        for (int j=0;j<8;j++) a8[j] += w2*bf2f((u16)e2[j]);
        #pragma unroll
        for (int j=0;j<8;j++) a8[j] += w3*bf2f((u16)e3[j]);
      }
      for (; ii < ne; ii += 4){
        s8 e0 = *(const s8*)(eb2 + (size_t)ii*Hd);
        float w0 = scl[ii];
        #pragma unroll
        for (int j=0;j<8;j++) a8[j] += w0*bf2f((u16)e0[j]);
      }
      { f4 v0 = {a8[0],a8[1],a8[2],a8[3]}, v1 = {a8[4],a8[5],a8[6],a8[7]};
        *(f4*)(part + wv*512 + l*8)     = v0;
        *(f4*)(part + wv*512 + l*8 + 4) = v1; }
      __syncthreads();
      {
        int h0 = 2*tid;
        float a0 = part[h0] + part[512+h0] + part[1024+h0] + part[1536+h0];
        float a1 = part[h0+1] + part[512+h0+1] + part[1024+h0+1] + part[1536+h0+1];
        st32a(pacc16 + (size_t)(rowA*2+halfA)*Hd + h0, (u32)f2bf(a0) | ((u32)f2bf(a1) << 16));
        if (tid == 0){
          union { u64 q; float f[2]; } pk; pk.f[0]=M; pk.f[1]=S;
          st64a(pms + rowA*2 + halfA, pk.q);
        }
      }
      __syncthreads();
      if (t >= 1) CEREC(t-1);
      if (t >= 2 && halfA == 0 && tid == 0) COMB(t-2);
      // prefetch next step's P1 h-fragments (hnew written before last RGB -> safe)
      if (t < Le-2){
        if (k2 == 0){
          #pragma unroll
          for (int ks = 4; ks < 18; ks++)
            aH[ks-4] = ld16a(hnew + (size_t)ar*Hd + (ks*32 + kl - 128));
        } else {
          aH[0] = ld16a(hnew + (size_t)ar*Hd + (448 + kl));
          aH[1] = ld16a(hnew + (size_t)ar*Hd + (480 + kl));
        }
      }
    }
    RGB();
  }

  // ================= epilogue =================
  const int TL = Le-2;   // 510
  // E1: Vnew_{510} + tanh (all WGs)
  {
    if (tid < 16){
      union { u64 q; float f[2]; } uA, uB;
      uA.q = ld64a(pms + (rg*16+tid)*2 + 0);
      uB.q = ld64a(pms + (rg*16+tid)*2 + 1);
      float M = fmaxf(uA.f[0], uB.f[0]);
      float eA = (uA.f[0] > -1e29f) ? expf(uA.f[0]-M) : 0.f;
      float eB = (uB.f[0] > -1e29f) ? expf(uB.f[0]-M) : 0.f;
      float den = uA.f[1]*eA + uB.f[1]*eB;
      sc2[tid*2]   = eA/den;
      sc2[tid*2+1] = eB/den;
    }
    __syncthreads();
    const float scA = sc2[(l&15)*2], scB = sc2[(l&15)*2+1];
    const u16* h5 = hbf + (size_t)((TL+1)&1)*Bv*Hd;
    const u16* pA = pacc16 + (size_t)(ar*2+0)*Hd;
    const u16* pB = pacc16 + (size_t)(ar*2+1)*Hd;
    const int colc = cg*16 + (l&15);
    f4 vac = {0,0,0,0};
    #pragma unroll
    for (int j = 0; j < 8; j++){
      int kv = k2*16 + j*2 + n2;
      s8 af;
      if (kv < 16) af = ld16a(h5 + (size_t)ar*Hd + kv*32 + kl);
      else {
        s8 va = ld16a(pA + (kv-16)*32 + kl);
        s8 vb = ld16a(pB + (kv-16)*32 + kl);
        #pragma unroll
        for (int q = 0; q < 8; q++)
          af[q] = (short)f2bf(scA*bf2f((u16)va[q]) + scB*bf2f((u16)vb[q]));
      }
      vac = MM(af, *(const s8*)(outw + (size_t)colc*1024 + kv*32 + kl), vac);
    }
    #pragma unroll
    for (int r = 0; r < 4; r++)
      vex[wv*256 + (((l>>4)<<2)+r)*16 + (l&15)] = vac[r];
    __syncthreads();
    {
      int row = tid >> 4, u = tid & 15;
      int gb = cg*16 + u;
      float v = vex[row*16+u] + vex[256+row*16+u] + vex[512+row*16+u]
              + vex[768+row*16+u] + p.outb[gb];
      u32 tb2 = f2bf(tanhf(v));
      u32 tn2 = __shfl_xor((int)tb2, 1, 64);
      if ((tid & 1) == 0){
        u16* tnw = tnhb + (size_t)(TL&1)*Bv*Hd;
        st32a(tnw + (size_t)(rg*16+row)*Hd + gb, tb2 | (tn2 << 16));
      }
    }
  }
  RGB();
  // E2: CE record for step 510 + combine 509
  {
    CEREC(TL);
    if (halfA == 0 && tid == 0) COMB(TL-1);
  }
  RGB();
  // E3: combine step 510, then accumulate loss
  {
    if (halfA == 0 && tid == 0){
      COMB(TL);
      atomicAdd(losp + 0, accN);
      atomicAdd(losp + 1, accC);
    }
  }
  GBall();
  if (wg == 0 && tid == 0) p.out[0] = losp[0] / fmaxf(losp[1], 1.f);
}

extern "C" void kernel_launch(void* const* d_in, const int* in_sizes, int n_in,
                              void* d_out, int out_size, void* d_ws, size_t ws_size,
                              hipStream_t stream)
{
  hipFuncSetAttribute(reinterpret_cast<const void*>(k_main),
                      hipFuncAttributeMaxDynamicSharedMemorySize, SM_BYTES);
  hipMemsetAsync(d_ws, 0, 4096, stream);

  P prm;
  prm.C    = (const float*)d_in[0];
  prm.Cpad = (const int*)  d_in[1];
  prm.E    = (const int*)  d_in[2];
  prm.Eemb = (const float*)d_in[3];
  prm.eWih = (const float*)d_in[4];
  prm.eWhh = (const float*)d_in[5];
  prm.ebih = (const float*)d_in[6];
  prm.ebhh = (const float*)d_in[7];
  prm.dWih = (const float*)d_in[8];
  prm.dWhh = (const float*)d_in[9];
  prm.dbih = (const float*)d_in[10];
  prm.dbhh = (const float*)d_in[11];
  prm.attW = (const float*)d_in[12];
  prm.outW = (const float*)d_in[13];
  prm.outb = (const float*)d_in[14];
  prm.vocW = (const float*)d_in[15];
  prm.vocb = (const float*)d_in[16];
  prm.ws   = (char*)d_ws;
  prm.out  = (float*)d_out;

  k_main<<<dim3(NWG), dim3(NT), SM_BYTES, stream>>>(prm);
}